// Round 1
// baseline (12761.563 us; speedup 1.0000x reference)
//
#include <hip/hip_runtime.h>

// Seq2SeqBridge: persistent cooperative kernel, f16 MFMA, register-resident weights.
// Grid: 256 WGs x 512 threads (1 WG/CU, 8 waves). Two independent batch-groups
// (16 batches each) with separate 128-WG barrier domains.

typedef _Float16 f16;
typedef _Float16 hvec8 __attribute__((ext_vector_type(8)));
typedef float fvec4 __attribute__((ext_vector_type(4)));

#define WS_H0   4096
#define WS_H1   135168
#define WS_HE   266240
#define WS_DEC  397312
#define WS_Y0   17174528
// total ws use: 33,951,744 bytes

__device__ __forceinline__ fvec4 mf(hvec8 a, hvec8 b, fvec4 c) {
    return __builtin_amdgcn_mfma_f32_16x16x32_f16(a, b, c, 0, 0, 0);
}

__device__ __forceinline__ hvec8 ldb8(const float* p) {
    hvec8 h;
#pragma unroll
    for (int j = 0; j < 8; ++j) h[j] = (f16)p[j];
    return h;
}

__device__ __forceinline__ float sigf(float x) { return 1.f / (1.f + __expf(-x)); }
__device__ __forceinline__ float thf(float x) {
    x = fminf(15.f, fmaxf(-15.f, x));
    float e = __expf(2.f * x);
    return (e - 1.f) / (e + 1.f);
}

__global__ void __launch_bounds__(512, 2)
seq2seq_kernel(const float* __restrict__ enc_h, const float* __restrict__ enc_c,
               const float* __restrict__ emb_W,
               const float* __restrict__ dWih0, const float* __restrict__ dWhh0,
               const float* __restrict__ dbih0, const float* __restrict__ dbhh0,
               const float* __restrict__ dWih1, const float* __restrict__ dWhh1,
               const float* __restrict__ dbih1, const float* __restrict__ dbhh1,
               const float* __restrict__ eWih, const float* __restrict__ eWhh,
               const float* __restrict__ ebih, const float* __restrict__ ebhh,
               float* __restrict__ out, char* __restrict__ ws)
{
    const int tid  = threadIdx.x;
    const int wave = tid >> 6, lane = tid & 63;
    const int wg   = blockIdx.x;
    const int bg   = wg >> 7;        // batch group (batches 16*bg .. 16*bg+15)
    const int g    = wg & 127;       // index within group
    const int n16  = lane & 15;      // MFMA frag row/col within tile
    const int kq   = (lane >> 4) * 8;

    unsigned* ctr = (unsigned*)(ws + bg * 256);
    f16* H0  = (f16*)(ws + WS_H0);    // [2 par][32][1024]
    f16* H1  = (f16*)(ws + WS_H1);    // [2 par][32][1024]
    f16* HE  = (f16*)(ws + WS_HE);    // [2 dir][2 par][32][512]
    f16* DEC = (f16*)(ws + WS_DEC);   // [256][32][1024] decoder h1 sequence
    f16* Y0  = (f16*)(ws + WS_Y0);    // [256][32][1024] encoder L0 output

    __shared__ float red[4 * 16 * 16 * 8];  // per-wave partial gate tiles
    __shared__ float red2[4 * 16 * 16];     // K-reduced gate tiles
    __shared__ float cdec[2][8][16];        // decoder cell state (L0,L1)[unit][batch]
    __shared__ float cenc[8][16];           // encoder cell state
    __shared__ float pre0_l[32];            // x0@Wih0^T + biases (decoder L0)
    __shared__ float bias1_l[32];           // decoder L1 biases
    __shared__ float biasE_l[32];           // encoder biases

    unsigned bcount = 0;
    auto gbar = [&]() {
        __syncthreads();                 // drains each wave's vmem (stores in L2)
        ++bcount;
        if (tid == 0) {
            // release: wbL2 so other XCDs see our stores via LLC
            __hip_atomic_fetch_add(ctr, 1u, __ATOMIC_RELEASE, __HIP_MEMORY_SCOPE_AGENT);
            const unsigned tgt = bcount * 128u;
            while (__hip_atomic_load(ctr, __ATOMIC_ACQUIRE, __HIP_MEMORY_SCOPE_AGENT) < tgt)
                __builtin_amdgcn_s_sleep(1);
        }
        __syncthreads();
    };

    // ---------------- P0: load decoder weight fragments into registers ----------
    const int u0 = g * 8;                   // this WG's 8 units (per layer)
    hvec8 bL0[2][4], bL1[2][8];
    {
        const int gate = n16 >> 2, uu = n16 & 3;
#pragma unroll
        for (int t = 0; t < 2; ++t) {
            const int r = gate * 1024 + u0 + t * 4 + uu;   // row in [4096]
#pragma unroll
            for (int s = 0; s < 4; ++s)
                bL0[t][s] = ldb8(dWhh0 + (size_t)r * 1024 + wave * 128 + s * 32 + kq);
#pragma unroll
            for (int s = 0; s < 8; ++s) {
                const int k1 = wave * 256 + s * 32;
                bL1[t][s] = (k1 < 1024)
                    ? ldb8(dWih1 + (size_t)r * 1024 + k1 + kq)
                    : ldb8(dWhh1 + (size_t)r * 1024 + (k1 - 1024) + kq);
            }
        }
    }
    // ---------------- P0: state init + pre0/biases -------------------------------
    if (tid < 256) {
        const int which = tid >> 7;             // 0: layer0, 1: layer1
        const int q = tid & 127;
        const int uu = q >> 4, m = q & 15;
        const int b = bg * 16 + m, u = u0 + uu;
        cdec[which][uu][m] = enc_c[(size_t)(which * 32 + b) * 1024 + u];
        f16* dst = which ? H1 : H0;
        dst[(size_t)(32 + b) * 1024 + u] = (f16)enc_h[(size_t)(which * 32 + b) * 1024 + u]; // parity 1
    }
    if (tid < 32) {
        const int t = tid >> 4, nn = tid & 15;
        const int r = (nn >> 2) * 1024 + u0 + t * 4 + (nn & 3);
        const float* x0 = emb_W + 512;          // emb_W[BOS=1]
        float s = dbih0[r] + dbhh0[r];
        const float* wr = dWih0 + (size_t)r * 512;
        for (int k = 0; k < 512; ++k) s += wr[k] * x0[k];
        pre0_l[tid]  = s;
        bias1_l[tid] = dbih1[r] + dbhh1[r];
    }
    gbar();

    // ---------------- decoder: 257 pipelined ticks -------------------------------
    // tick tau: L0 computes h0[tau] (reads h0[tau-1]); L1 computes h1[tau-1]
    // (reads h0[tau-1], h1[tau-2]).
    for (int tau = 0; tau <= 256; ++tau) {
        const int prd = (tau + 1) & 1;   // h0 read parity (state tau-1); h1 write parity
        const int pwr = tau & 1;         // h0 write parity; h1 read parity (state tau-2)
        fvec4 acc[4];
#pragma unroll
        for (int i = 0; i < 4; ++i) acc[i] = 0;
        const int m = n16;
        if (tau < 256) {
            const f16* a0 = H0 + (size_t)(prd * 32 + bg * 16 + m) * 1024 + wave * 128 + kq;
#pragma unroll
            for (int s = 0; s < 4; ++s) {
                hvec8 a = *(const hvec8*)(a0 + s * 32);
                acc[0] = mf(a, bL0[0][s], acc[0]);
                acc[1] = mf(a, bL0[1][s], acc[1]);
            }
        }
        if (tau >= 1) {
            const f16* a1 = (wave < 4)
                ? H0 + (size_t)(prd * 32 + bg * 16 + m) * 1024 + wave * 256 + kq
                : H1 + (size_t)(pwr * 32 + bg * 16 + m) * 1024 + (wave - 4) * 256 + kq;
#pragma unroll
            for (int s = 0; s < 8; ++s) {
                hvec8 a = *(const hvec8*)(a1 + s * 32);
                acc[2] = mf(a, bL1[0][s], acc[2]);
                acc[3] = mf(a, bL1[1][s], acc[3]);
            }
        }
        {
            const int mg = lane >> 4;
#pragma unroll
            for (int t = 0; t < 4; ++t)
#pragma unroll
                for (int r = 0; r < 4; ++r)
                    red[(((t * 16 + (mg * 4 + r)) * 16 + n16) * 8) + wave] = acc[t][r];
        }
        __syncthreads();
        for (int it = tid; it < 1024; it += 512) {
            const float* p = red + it * 8;
            red2[it] = ((p[0] + p[1]) + (p[2] + p[3])) + ((p[4] + p[5]) + (p[6] + p[7]));
        }
        __syncthreads();
        if (tid < 128 && tau < 256) {                       // L0 pointwise
            const int uu = tid >> 4, m2 = tid & 15;
            const int t = uu >> 2, ul = uu & 3;
            const int base = t * 256 + m2 * 16;
            const float gi = red2[base + ul]      + pre0_l[t * 16 + ul];
            const float gf = red2[base + 4 + ul]  + pre0_l[t * 16 + 4 + ul];
            const float gg = red2[base + 8 + ul]  + pre0_l[t * 16 + 8 + ul];
            const float go = red2[base + 12 + ul] + pre0_l[t * 16 + 12 + ul];
            float c = cdec[0][uu][m2];
            c = sigf(gf) * c + sigf(gi) * thf(gg);
            const float h = sigf(go) * thf(c);
            cdec[0][uu][m2] = c;
            H0[(size_t)(pwr * 32 + bg * 16 + m2) * 1024 + u0 + uu] = (f16)h;
        } else if (tid >= 128 && tid < 256 && tau >= 1) {   // L1 pointwise
            const int q = tid - 128;
            const int uu = q >> 4, m2 = q & 15;
            const int t = uu >> 2, ul = uu & 3;
            const int base = (2 + t) * 256 + m2 * 16;
            const float gi = red2[base + ul]      + bias1_l[t * 16 + ul];
            const float gf = red2[base + 4 + ul]  + bias1_l[t * 16 + 4 + ul];
            const float gg = red2[base + 8 + ul]  + bias1_l[t * 16 + 8 + ul];
            const float go = red2[base + 12 + ul] + bias1_l[t * 16 + 12 + ul];
            float c = cdec[1][uu][m2];
            c = sigf(gf) * c + sigf(gi) * thf(gg);
            const float h = sigf(go) * thf(c);
            cdec[1][uu][m2] = c;
            const int b = bg * 16 + m2, u = u0 + uu;
            H1[(size_t)(prd * 32 + b) * 1024 + u] = (f16)h;
            DEC[((size_t)(tau - 1) * 32 + b) * 1024 + u] = (f16)h;
        }
        gbar();
    }

    // ---------------- encoder: 2 layers x 256 ticks, fwd/bwd concurrent ----------
    const int dir = g >> 6;          // 0 fwd, 1 bwd
    const int ge  = g & 63;
    const int ue0 = ge * 8;          // this WG's 8 units (of 512)
    for (int l = 0; l < 2; ++l) {
        hvec8 bE[2][6];
        {
            const int gate = n16 >> 2, uu = n16 & 3;
            const float* Wih = eWih + (size_t)(l * 2 + dir) * 2048 * 1024;
            const float* Whh = eWhh + (size_t)(l * 2 + dir) * 2048 * 512;
#pragma unroll
            for (int t = 0; t < 2; ++t) {
                const int r = gate * 512 + ue0 + t * 4 + uu;
#pragma unroll
                for (int s = 0; s < 6; ++s) {
                    const int kb = wave * 192 + s * 32;
                    bE[t][s] = (kb < 1024)
                        ? ldb8(Wih + (size_t)r * 1024 + kb + kq)
                        : ldb8(Whh + (size_t)r * 512 + (kb - 1024) + kq);
                }
            }
        }
        if (tid < 32) {
            const int t = tid >> 4, nn = tid & 15;
            const int r = (nn >> 2) * 512 + ue0 + t * 4 + (nn & 3);
            biasE_l[tid] = ebih[(size_t)(l * 2 + dir) * 2048 + r]
                         + ebhh[(size_t)(l * 2 + dir) * 2048 + r];
        }
        if (tid < 128) {
            const int uu = tid >> 4, m = tid & 15;
            cenc[uu][m] = 0.f;
            HE[(size_t)((dir * 2 + 1) * 32 + bg * 16 + m) * 512 + ue0 + uu] = (f16)0.f;
        }
        gbar();
        const f16* yprev = (l == 0) ? DEC : Y0;
        for (int tau = 0; tau < 256; ++tau) {
            const int t = dir ? (255 - tau) : tau;
            const int prd = (tau + 1) & 1, pwr = tau & 1;
            fvec4 acc2[2];
            acc2[0] = 0; acc2[1] = 0;
            const int m = n16, b = bg * 16 + m;
#pragma unroll
            for (int s = 0; s < 6; ++s) {
                const int kb = wave * 192 + s * 32;
                const f16* p = (kb < 1024)
                    ? yprev + ((size_t)t * 32 + b) * 1024 + kb + kq
                    : HE + (size_t)((dir * 2 + prd) * 32 + b) * 512 + (kb - 1024) + kq;
                hvec8 a = *(const hvec8*)p;
                acc2[0] = mf(a, bE[0][s], acc2[0]);
                acc2[1] = mf(a, bE[1][s], acc2[1]);
            }
            const int mg = lane >> 4;
#pragma unroll
            for (int tt = 0; tt < 2; ++tt)
#pragma unroll
                for (int r = 0; r < 4; ++r)
                    red[(((tt * 16 + (mg * 4 + r)) * 16 + n16) * 8) + wave] = acc2[tt][r];
            __syncthreads();
            {
                const float* p = red + tid * 8;   // 512 items, tiles 0..1
                red2[tid] = ((p[0] + p[1]) + (p[2] + p[3])) + ((p[4] + p[5]) + (p[6] + p[7]));
            }
            __syncthreads();
            if (tid < 128) {
                const int uu = tid >> 4, m2 = tid & 15;
                const int tt = uu >> 2, ul = uu & 3;
                const int base = tt * 256 + m2 * 16;
                const float gi = red2[base + ul]      + biasE_l[tt * 16 + ul];
                const float gf = red2[base + 4 + ul]  + biasE_l[tt * 16 + 4 + ul];
                const float gg = red2[base + 8 + ul]  + biasE_l[tt * 16 + 8 + ul];
                const float go = red2[base + 12 + ul] + biasE_l[tt * 16 + 12 + ul];
                float c = cenc[uu][m2];
                c = sigf(gf) * c + sigf(gi) * thf(gg);
                const float h = sigf(go) * thf(c);
                cenc[uu][m2] = c;
                const int b2 = bg * 16 + m2, u = ue0 + uu;
                HE[(size_t)((dir * 2 + pwr) * 32 + b2) * 512 + u] = (f16)h;
                if (l == 0) {
                    Y0[((size_t)t * 32 + b2) * 1024 + dir * 512 + u] = (f16)h;
                } else {
                    out[((size_t)b2 * 256 + t) * 1024 + dir * 512 + u] = h;
                    if (tau == 255) {   // final states -> dec_h / dec_c (both layer copies)
                        const int col = dir * 512 + u;
                        out[8388608 + (size_t)(0 * 32 + b2) * 1024 + col] = h;
                        out[8388608 + (size_t)(1 * 32 + b2) * 1024 + col] = h;
                        out[8454144 + (size_t)(0 * 32 + b2) * 1024 + col] = c;
                        out[8454144 + (size_t)(1 * 32 + b2) * 1024 + col] = c;
                    }
                }
            }
            gbar();
        }
    }
}

extern "C" void kernel_launch(void* const* d_in, const int* in_sizes, int n_in,
                              void* d_out, int out_size, void* d_ws, size_t ws_size,
                              hipStream_t stream) {
    (void)in_sizes; (void)n_in; (void)out_size; (void)ws_size;
    const float* enc_h = (const float*)d_in[1];
    const float* enc_c = (const float*)d_in[2];
    const float* emb_W = (const float*)d_in[4];
    const float* dWih0 = (const float*)d_in[5];
    const float* dWhh0 = (const float*)d_in[6];
    const float* dbih0 = (const float*)d_in[7];
    const float* dbhh0 = (const float*)d_in[8];
    const float* dWih1 = (const float*)d_in[9];
    const float* dWhh1 = (const float*)d_in[10];
    const float* dbih1 = (const float*)d_in[11];
    const float* dbhh1 = (const float*)d_in[12];
    const float* eWih  = (const float*)d_in[13];
    const float* eWhh  = (const float*)d_in[14];
    const float* ebih  = (const float*)d_in[15];
    const float* ebhh  = (const float*)d_in[16];
    float* outp = (float*)d_out;
    char* ws = (char*)d_ws;

    // zero the barrier counters (ws is poisoned before every launch)
    hipMemsetAsync(d_ws, 0, 4096, stream);

    void* args[] = {&enc_h, &enc_c, &emb_W, &dWih0, &dWhh0, &dbih0, &dbhh0,
                    &dWih1, &dWhh1, &dbih1, &dbhh1, &eWih, &eWhh, &ebih, &ebhh,
                    &outp, &ws};
    hipLaunchCooperativeKernel((const void*)seq2seq_kernel, dim3(256), dim3(512),
                               args, 0, stream);
}

// Round 2
// 4893.240 us; speedup vs baseline: 2.6080x; 2.6080x over previous
//
#include <hip/hip_runtime.h>

// Seq2SeqBridge: persistent cooperative kernel, f16 MFMA, register-resident weights.
// All cross-WG state goes through sc1 (L2-bypass, LLC-coherent) relaxed atomics;
// barriers are relaxed monotone counters -> no buffer_wbl2/buffer_inv per tick.

typedef _Float16 f16;
typedef _Float16 hvec8 __attribute__((ext_vector_type(8)));
typedef float fvec4 __attribute__((ext_vector_type(4)));

#define WS_H0   4096
#define WS_H1   135168
#define WS_HE   266240
#define WS_DEC  397312
#define WS_Y0   17174528
// total ws use: 33,951,744 bytes

__device__ __forceinline__ fvec4 mf(hvec8 a, hvec8 b, fvec4 c) {
    return __builtin_amdgcn_mfma_f32_16x16x32_f16(a, b, c, 0, 0, 0);
}

// weights: normal cached loads (read-only, converted once into registers)
__device__ __forceinline__ hvec8 ldb8(const float* p) {
    hvec8 h;
#pragma unroll
    for (int j = 0; j < 8; ++j) h[j] = (f16)p[j];
    return h;
}

// cross-WG state: relaxed agent-scope atomics -> global_load/store sc1 (bypass L2)
__device__ __forceinline__ hvec8 lda8(const f16* p) {
    union { unsigned long long u[2]; hvec8 h; } x;
    x.u[0] = __hip_atomic_load((const unsigned long long*)p,     __ATOMIC_RELAXED, __HIP_MEMORY_SCOPE_AGENT);
    x.u[1] = __hip_atomic_load((const unsigned long long*)p + 1, __ATOMIC_RELAXED, __HIP_MEMORY_SCOPE_AGENT);
    return x.h;
}
__device__ __forceinline__ void st2(f16* p, float a, float b) {
    union { f16 h[2]; unsigned u; } x;
    x.h[0] = (f16)a; x.h[1] = (f16)b;
    __hip_atomic_store((unsigned*)p, x.u, __ATOMIC_RELAXED, __HIP_MEMORY_SCOPE_AGENT);
}

__device__ __forceinline__ float sigf(float x) { return 1.f / (1.f + __expf(-x)); }
__device__ __forceinline__ float thf(float x) {
    x = fminf(15.f, fmaxf(-15.f, x));
    float e = __expf(2.f * x);
    return (e - 1.f) / (e + 1.f);
}

// LDS layouts: RED row stride 132 (2-way bank conflicts only), RED2 stride 20
#define RED(t, m, w, n)  red[(((t)*16 + (m))*132) + ((w)*16) + (n)]
#define RED2(t, m, n)    red2[(((t)*16 + (m))*20) + (n)]

__global__ void __launch_bounds__(512, 1)
seq2seq_kernel(const float* __restrict__ enc_h, const float* __restrict__ enc_c,
               const float* __restrict__ emb_W,
               const float* __restrict__ dWih0, const float* __restrict__ dWhh0,
               const float* __restrict__ dbih0, const float* __restrict__ dbhh0,
               const float* __restrict__ dWih1, const float* __restrict__ dWhh1,
               const float* __restrict__ dbih1, const float* __restrict__ dbhh1,
               const float* __restrict__ eWih, const float* __restrict__ eWhh,
               const float* __restrict__ ebih, const float* __restrict__ ebhh,
               float* __restrict__ out, char* __restrict__ ws)
{
    const int tid  = threadIdx.x;
    const int wave = tid >> 6, lane = tid & 63;
    const int wg   = blockIdx.x;
    const int bg   = wg >> 7;        // batch group (batches 16*bg .. 16*bg+15)
    const int g    = wg & 127;       // index within group
    const int n16  = lane & 15;
    const int kq   = (lane >> 4) * 8;

    unsigned* ctrG = (unsigned*)(ws + bg * 128);
    f16* H0  = (f16*)(ws + WS_H0);    // [2 par][32][1024]
    f16* H1  = (f16*)(ws + WS_H1);    // [2 par][32][1024]
    f16* HE  = (f16*)(ws + WS_HE);    // [2 dir][2 par][32][512]
    f16* DEC = (f16*)(ws + WS_DEC);   // [256][32][1024]
    f16* Y0  = (f16*)(ws + WS_Y0);    // [256][32][1024]

    __shared__ float red[64 * 132];
    __shared__ float red2[64 * 20];
    __shared__ float cdec[2][8][16];
    __shared__ float cenc[8][16];
    __shared__ float pre0_l[32];
    __shared__ float bias1_l[32];
    __shared__ float biasE_l[32];

    unsigned cntG = 0, cntD = 0;
    auto bar = [&](unsigned* c, unsigned tgt) {
        __syncthreads();   // compiler emits s_waitcnt vmcnt(0) before s_barrier:
        if (tid == 0) {    // all this WG's sc1 stores are LLC-visible here
            __hip_atomic_fetch_add(c, 1u, __ATOMIC_RELAXED, __HIP_MEMORY_SCOPE_AGENT);
            while (__hip_atomic_load(c, __ATOMIC_RELAXED, __HIP_MEMORY_SCOPE_AGENT) < tgt)
                __builtin_amdgcn_s_sleep(2);
        }
        __syncthreads();
    };

    // ---------------- P0: decoder weight fragments -> registers -----------------
    const int u0 = g * 8;
    hvec8 bL0[2][4], bL1[2][8];
    {
        const int gate = n16 >> 2, uu = n16 & 3;
#pragma unroll
        for (int t = 0; t < 2; ++t) {
            const int r = gate * 1024 + u0 + t * 4 + uu;
#pragma unroll
            for (int s = 0; s < 4; ++s)
                bL0[t][s] = ldb8(dWhh0 + (size_t)r * 1024 + wave * 128 + s * 32 + kq);
#pragma unroll
            for (int s = 0; s < 8; ++s) {
                const int k1 = wave * 256 + s * 32;
                bL1[t][s] = (k1 < 1024)
                    ? ldb8(dWih1 + (size_t)r * 1024 + k1 + kq)
                    : ldb8(dWhh1 + (size_t)r * 1024 + (k1 - 1024) + kq);
            }
        }
    }
    // ---------------- P0: state init + pre0/biases -------------------------------
    if (tid < 128) {
        const int which = tid >> 6, q = tid & 63, j = q >> 4, m = q & 15;
        const int b = bg * 16 + m, u = u0 + 2 * j;
        const float* src_c = enc_c + (size_t)(which * 32 + b) * 1024 + u;
        const float* src_h = enc_h + (size_t)(which * 32 + b) * 1024 + u;
        cdec[which][2 * j][m]     = src_c[0];
        cdec[which][2 * j + 1][m] = src_c[1];
        f16* dst = which ? H1 : H0;
        st2(dst + (size_t)(32 + b) * 1024 + u, src_h[0], src_h[1]);  // parity 1
    }
    if (tid < 32) {
        const int t = tid >> 4, nn = tid & 15;
        const int r = (nn >> 2) * 1024 + u0 + t * 4 + (nn & 3);
        const float* x0 = emb_W + 512;          // emb_W[BOS=1]
        float s = dbih0[r] + dbhh0[r];
        const float* wr = dWih0 + (size_t)r * 512;
        for (int k = 0; k < 512; ++k) s += wr[k] * x0[k];
        pre0_l[tid]  = s;
        bias1_l[tid] = dbih1[r] + dbhh1[r];
    }
    bar(ctrG, ++cntG * 128u);

    // ---------------- decoder: 257 pipelined ticks -------------------------------
    for (int tau = 0; tau <= 256; ++tau) {
        const int prd = (tau + 1) & 1;   // h0 read parity; h1 write parity
        const int pwr = tau & 1;         // h0 write parity; h1 read parity
        fvec4 acc[4];
#pragma unroll
        for (int i = 0; i < 4; ++i) acc[i] = 0;
        const int m = n16;
        if (tau < 256) {
            const f16* a0 = H0 + (size_t)(prd * 32 + bg * 16 + m) * 1024 + wave * 128 + kq;
#pragma unroll
            for (int s = 0; s < 4; ++s) {
                hvec8 a = lda8(a0 + s * 32);
                acc[0] = mf(a, bL0[0][s], acc[0]);
                acc[1] = mf(a, bL0[1][s], acc[1]);
            }
        }
        if (tau >= 1) {
            const f16* a1 = (wave < 4)
                ? H0 + (size_t)(prd * 32 + bg * 16 + m) * 1024 + wave * 256 + kq
                : H1 + (size_t)(pwr * 32 + bg * 16 + m) * 1024 + (wave - 4) * 256 + kq;
#pragma unroll
            for (int s = 0; s < 8; ++s) {
                hvec8 a = lda8(a1 + s * 32);
                acc[2] = mf(a, bL1[0][s], acc[2]);
                acc[3] = mf(a, bL1[1][s], acc[3]);
            }
        }
        {
            const int mg = lane >> 4;
#pragma unroll
            for (int t = 0; t < 4; ++t)
#pragma unroll
                for (int r = 0; r < 4; ++r)
                    RED(t, mg * 4 + r, wave, n16) = acc[t][r];
        }
        __syncthreads();
        for (int it = tid; it < 1024; it += 512) {
            const int t = it >> 8, mm = it & 15, nn = (it >> 4) & 15;
            const float* p = &RED(t, mm, 0, nn);
            RED2(t, mm, nn) = ((p[0] + p[16]) + (p[32] + p[48]))
                            + ((p[64] + p[80]) + (p[96] + p[112]));
        }
        __syncthreads();
        if (tid < 64 && tau < 256) {                       // L0 pointwise (wave 0)
            const int j = tid >> 4, m2 = tid & 15, t = j >> 1;
            float hh[2];
#pragma unroll
            for (int e = 0; e < 2; ++e) {
                const int uu = 2 * j + e, ul = uu & 3;
                const float gi = RED2(t, m2, ul)      + pre0_l[t * 16 + ul];
                const float gf = RED2(t, m2, 4 + ul)  + pre0_l[t * 16 + 4 + ul];
                const float gg = RED2(t, m2, 8 + ul)  + pre0_l[t * 16 + 8 + ul];
                const float go = RED2(t, m2, 12 + ul) + pre0_l[t * 16 + 12 + ul];
                float c = cdec[0][uu][m2];
                c = sigf(gf) * c + sigf(gi) * thf(gg);
                hh[e] = sigf(go) * thf(c);
                cdec[0][uu][m2] = c;
            }
            st2(H0 + (size_t)(pwr * 32 + bg * 16 + m2) * 1024 + u0 + 2 * j, hh[0], hh[1]);
        }
        if (tid >= 64 && tid < 128 && tau >= 1) {          // L1 pointwise (wave 1)
            const int q = tid - 64;
            const int j = q >> 4, m2 = q & 15, t = j >> 1;
            float hh[2];
#pragma unroll
            for (int e = 0; e < 2; ++e) {
                const int uu = 2 * j + e, ul = uu & 3;
                const float gi = RED2(2 + t, m2, ul)      + bias1_l[t * 16 + ul];
                const float gf = RED2(2 + t, m2, 4 + ul)  + bias1_l[t * 16 + 4 + ul];
                const float gg = RED2(2 + t, m2, 8 + ul)  + bias1_l[t * 16 + 8 + ul];
                const float go = RED2(2 + t, m2, 12 + ul) + bias1_l[t * 16 + 12 + ul];
                float c = cdec[1][uu][m2];
                c = sigf(gf) * c + sigf(gi) * thf(gg);
                hh[e] = sigf(go) * thf(c);
                cdec[1][uu][m2] = c;
            }
            const int b = bg * 16 + m2, u = u0 + 2 * j;
            st2(H1 + (size_t)(prd * 32 + b) * 1024 + u, hh[0], hh[1]);
            st2(DEC + ((size_t)(tau - 1) * 32 + b) * 1024 + u, hh[0], hh[1]);
        }
        bar(ctrG, ++cntG * 128u);
    }

    // ---------------- encoder: 2 layers x 256 ticks, fwd/bwd in own domains ------
    const int dir = g >> 6;
    const int ge  = g & 63;
    const int ue0 = ge * 8;
    unsigned* ctrD = (unsigned*)(ws + 512 + (bg * 2 + dir) * 128);
    for (int l = 0; l < 2; ++l) {
        hvec8 bE[2][6];
        {
            const int gate = n16 >> 2, uu = n16 & 3;
            const float* Wih = eWih + (size_t)(l * 2 + dir) * 2048 * 1024;
            const float* Whh = eWhh + (size_t)(l * 2 + dir) * 2048 * 512;
#pragma unroll
            for (int t = 0; t < 2; ++t) {
                const int r = gate * 512 + ue0 + t * 4 + uu;
#pragma unroll
                for (int s = 0; s < 6; ++s) {
                    const int kb = wave * 192 + s * 32;
                    bE[t][s] = (kb < 1024)
                        ? ldb8(Wih + (size_t)r * 1024 + kb + kq)
                        : ldb8(Whh + (size_t)r * 512 + (kb - 1024) + kq);
                }
            }
        }
        if (tid < 32) {
            const int t = tid >> 4, nn = tid & 15;
            const int r = (nn >> 2) * 512 + ue0 + t * 4 + (nn & 3);
            biasE_l[tid] = ebih[(size_t)(l * 2 + dir) * 2048 + r]
                         + ebhh[(size_t)(l * 2 + dir) * 2048 + r];
        }
        if (tid < 64) {
            const int j = tid >> 4, m = tid & 15;
            cenc[2 * j][m] = 0.f;
            cenc[2 * j + 1][m] = 0.f;
            st2(HE + (size_t)((dir * 2 + 1) * 32 + bg * 16 + m) * 512 + ue0 + 2 * j, 0.f, 0.f);
        }
        bar(ctrD, ++cntD * 64u);
        const f16* yprev = (l == 0) ? DEC : Y0;
        for (int tau = 0; tau < 256; ++tau) {
            const int t = dir ? (255 - tau) : tau;
            const int prd = (tau + 1) & 1, pwr = tau & 1;
            fvec4 acc2[2];
            acc2[0] = 0; acc2[1] = 0;
            const int m = n16, b = bg * 16 + m;
#pragma unroll
            for (int s = 0; s < 6; ++s) {
                const int kb = wave * 192 + s * 32;
                const f16* p = (kb < 1024)
                    ? yprev + ((size_t)t * 32 + b) * 1024 + kb + kq
                    : HE + (size_t)((dir * 2 + prd) * 32 + b) * 512 + (kb - 1024) + kq;
                hvec8 a = lda8(p);
                acc2[0] = mf(a, bE[0][s], acc2[0]);
                acc2[1] = mf(a, bE[1][s], acc2[1]);
            }
            const int mg = lane >> 4;
#pragma unroll
            for (int tt = 0; tt < 2; ++tt)
#pragma unroll
                for (int r = 0; r < 4; ++r)
                    RED(tt, mg * 4 + r, wave, n16) = acc2[tt][r];
            __syncthreads();
            {
                const int t2 = tid >> 8, mm = tid & 15, nn = (tid >> 4) & 15;
                const float* p = &RED(t2, mm, 0, nn);
                RED2(t2, mm, nn) = ((p[0] + p[16]) + (p[32] + p[48]))
                                 + ((p[64] + p[80]) + (p[96] + p[112]));
            }
            __syncthreads();
            if (tid < 64) {
                const int j = tid >> 4, m2 = tid & 15, tt = j >> 1;
                float hh[2], cc[2];
#pragma unroll
                for (int e = 0; e < 2; ++e) {
                    const int uu = 2 * j + e, ul = uu & 3;
                    const float gi = RED2(tt, m2, ul)      + biasE_l[tt * 16 + ul];
                    const float gf = RED2(tt, m2, 4 + ul)  + biasE_l[tt * 16 + 4 + ul];
                    const float gg = RED2(tt, m2, 8 + ul)  + biasE_l[tt * 16 + 8 + ul];
                    const float go = RED2(tt, m2, 12 + ul) + biasE_l[tt * 16 + 12 + ul];
                    float c = cenc[uu][m2];
                    c = sigf(gf) * c + sigf(gi) * thf(gg);
                    hh[e] = sigf(go) * thf(c);
                    cc[e] = c;
                    cenc[uu][m2] = c;
                }
                const int b2 = bg * 16 + m2, u = ue0 + 2 * j;
                st2(HE + (size_t)((dir * 2 + pwr) * 32 + b2) * 512 + u, hh[0], hh[1]);
                if (l == 0) {
                    st2(Y0 + ((size_t)t * 32 + b2) * 1024 + dir * 512 + u, hh[0], hh[1]);
                } else {
                    float* o = out + ((size_t)b2 * 256 + t) * 1024 + dir * 512 + u;
                    o[0] = hh[0]; o[1] = hh[1];
                    if (tau == 255) {   // final states -> dec_h / dec_c
                        const int col = dir * 512 + u;
                        float* oh = out + 8388608 + (size_t)b2 * 1024 + col;
                        float* oc = out + 8454144 + (size_t)b2 * 1024 + col;
                        oh[0] = hh[0]; oh[1] = hh[1];
                        oh[32768] = hh[0]; oh[32769] = hh[1];
                        oc[0] = cc[0]; oc[1] = cc[1];
                        oc[32768] = cc[0]; oc[32769] = cc[1];
                    }
                }
            }
            bar(ctrD, ++cntD * 64u);
        }
        if (l == 0) bar(ctrG, ++cntG * 128u);  // Y0 (both dirs) complete
    }
}

extern "C" void kernel_launch(void* const* d_in, const int* in_sizes, int n_in,
                              void* d_out, int out_size, void* d_ws, size_t ws_size,
                              hipStream_t stream) {
    (void)in_sizes; (void)n_in; (void)out_size; (void)ws_size;
    const float* enc_h = (const float*)d_in[1];
    const float* enc_c = (const float*)d_in[2];
    const float* emb_W = (const float*)d_in[4];
    const float* dWih0 = (const float*)d_in[5];
    const float* dWhh0 = (const float*)d_in[6];
    const float* dbih0 = (const float*)d_in[7];
    const float* dbhh0 = (const float*)d_in[8];
    const float* dWih1 = (const float*)d_in[9];
    const float* dWhh1 = (const float*)d_in[10];
    const float* dbih1 = (const float*)d_in[11];
    const float* dbhh1 = (const float*)d_in[12];
    const float* eWih  = (const float*)d_in[13];
    const float* eWhh  = (const float*)d_in[14];
    const float* ebih  = (const float*)d_in[15];
    const float* ebhh  = (const float*)d_in[16];
    float* outp = (float*)d_out;
    char* ws = (char*)d_ws;

    // zero the barrier counters (ws is re-poisoned before every launch)
    hipMemsetAsync(d_ws, 0, 4096, stream);

    void* args[] = {&enc_h, &enc_c, &emb_W, &dWih0, &dWhh0, &dbih0, &dbhh0,
                    &dWih1, &dWhh1, &dbih1, &dbhh1, &eWih, &eWhh, &ebih, &ebhh,
                    &outp, &ws};
    hipLaunchCooperativeKernel((const void*)seq2seq_kernel, dim3(256), dim3(512),
                               args, 0, stream);
}